// Round 2
// baseline (786.861 us; speedup 1.0000x reference)
//
#include <hip/hip_runtime.h>

// GINEConv: out = (1+eps)*node_feat + segment_sum(relu(node_feat[src] + edge_feat), dst)
// N=50000, D=128, E=800000, fp32.
//
// R3: aggregate_kernel rewritten for memory-level parallelism. Avg degree is
// only 16, so the R1/R2 loop (2-4 edges/iter, dependent perm->ef chain) never
// had more than ~6 loads in flight per wave => latency-bound, not BW-bound.
// Now: lanes cooperatively load up to 16 perm entries in ONE coalesced int2
// load, __shfl-broadcast them, and issue all 32 ef/nf row loads back-to-back
// (independent). Nontemporal hints on streamed-once data (ef, perm, out) keep
// L2/LLC for nf (re-read ~16x).

#define D 128
#define DV2 64   // float2 chunks per row
#define BATCH 16

typedef float v2f __attribute__((ext_vector_type(2)));
typedef int   v2i __attribute__((ext_vector_type(2)));

// ---------- fallback path (R0) ----------
__global__ void init_out_kernel(const float4* __restrict__ nf,
                                const float* __restrict__ eps,
                                float4* __restrict__ out, int n4) {
    int i = blockIdx.x * blockDim.x + threadIdx.x;
    if (i >= n4) return;
    float s = 1.0f + eps[0];
    float4 v = nf[i];
    v.x *= s; v.y *= s; v.z *= s; v.w *= s;
    out[i] = v;
}

__global__ void edge_scatter_kernel(const float4* __restrict__ nf,
                                    const float4* __restrict__ ef,
                                    const int* __restrict__ src,
                                    const int* __restrict__ dst,
                                    float* __restrict__ out, int E_) {
    int t = blockIdx.x * blockDim.x + threadIdx.x;
    int e = t >> 5;
    int c = t & 31;
    if (e >= E_) return;
    int s = src[e];
    int d = dst[e];
    float4 a = ef[(size_t)e * 32 + c];
    float4 b = nf[(size_t)s * 32 + c];
    float4 m;
    m.x = fmaxf(a.x + b.x, 0.0f);
    m.y = fmaxf(a.y + b.y, 0.0f);
    m.z = fmaxf(a.z + b.z, 0.0f);
    m.w = fmaxf(a.w + b.w, 0.0f);
    float* o = out + (size_t)d * D + c * 4;
    atomicAdd(o + 0, m.x);
    atomicAdd(o + 1, m.y);
    atomicAdd(o + 2, m.z);
    atomicAdd(o + 3, m.w);
}

// ---------- CSR build ----------
__global__ void histogram_kernel(const int* __restrict__ dst, int* __restrict__ deg, int E_) {
    int e = blockIdx.x * blockDim.x + threadIdx.x;
    if (e >= E_) return;
    atomicAdd(&deg[dst[e]], 1);
}

// Single-block exclusive scan, thread-chunked (2 barriers total).
// deg may alias cursor: threads only touch their own chunk, read-before-write.
__global__ void scan_kernel(const int* __restrict__ deg, int* __restrict__ offs,
                            int* __restrict__ cursor, int n) {
    __shared__ int wsum[16];
    int t = threadIdx.x;
    int lane = t & 63;
    int w = t >> 6;
    int chunk = (n + 1023) >> 10;
    int begin = t * chunk; if (begin > n) begin = n;
    int endi = begin + chunk; if (endi > n) endi = n;

    int s = 0;
    for (int i = begin; i < endi; ++i) s += deg[i];

    int v = s;
    #pragma unroll
    for (int off = 1; off < 64; off <<= 1) {
        int u = __shfl_up(v, off);
        if (lane >= off) v += u;
    }
    if (lane == 63) wsum[w] = v;
    __syncthreads();
    if (t == 0) {
        int r = 0;
        #pragma unroll
        for (int i = 0; i < 16; ++i) { int tv = wsum[i]; wsum[i] = r; r += tv; }
    }
    __syncthreads();

    int run = wsum[w] + v - s;
    for (int i = begin; i < endi; ++i) {
        int d = deg[i];
        offs[i] = run;
        cursor[i] = run;
        run += d;
    }
    if (t == 1023) offs[n] = run;  // t=1023's chunk is empty -> run == total
}

__global__ void scatter_perm_kernel(const int* __restrict__ src, const int* __restrict__ dst,
                                    int* __restrict__ cursor,
                                    v2i* __restrict__ perm, int E_) {
    int e = blockIdx.x * blockDim.x + threadIdx.x;
    if (e >= E_) return;
    int d = dst[e];
    int pos = atomicAdd(&cursor[d], 1);
    v2i p; p.x = src[e]; p.y = e;
    perm[pos] = p;
}

// ---------- aggregation: one wave per node, batched independent loads ----------
__global__ void aggregate_kernel(const v2f* __restrict__ nf,
                                 const v2f* __restrict__ ef,
                                 const int* __restrict__ offs,
                                 const v2i* __restrict__ perm,
                                 const float* __restrict__ eps,
                                 v2f* __restrict__ out, int n) {
    int wid = (blockIdx.x * blockDim.x + threadIdx.x) >> 6;
    if (wid >= n) return;
    int lane = threadIdx.x & 63;

    int start = offs[wid];
    int end   = offs[wid + 1];

    float accx = 0.0f, accy = 0.0f;

    for (int i = start; i < end; i += BATCH) {
        int cnt = end - i; if (cnt > BATCH) cnt = BATCH;
        // one coalesced index load for the whole batch
        v2i pe; pe.x = 0; pe.y = 0;
        if (lane < cnt) pe = __builtin_nontemporal_load(&perm[i + lane]);
        // issue all row loads back-to-back: 2*cnt independent 512B wave-loads
        v2f a[BATCH], b[BATCH];
        #pragma unroll
        for (int j = 0; j < BATCH; ++j) {
            if (j < cnt) {
                int e = __shfl(pe.y, j);
                int s = __shfl(pe.x, j);
                a[j] = __builtin_nontemporal_load(&ef[(size_t)e * DV2 + lane]);
                b[j] = nf[(size_t)s * DV2 + lane];
            }
        }
        #pragma unroll
        for (int j = 0; j < BATCH; ++j) {
            if (j < cnt) {
                accx += fmaxf(a[j].x + b[j].x, 0.0f);
                accy += fmaxf(a[j].y + b[j].y, 0.0f);
            }
        }
    }

    float sc = 1.0f + eps[0];
    v2f self = nf[(size_t)wid * DV2 + lane];
    v2f o;
    o.x = sc * self.x + accx;
    o.y = sc * self.y + accy;
    __builtin_nontemporal_store(o, &out[(size_t)wid * DV2 + lane]);
}

extern "C" void kernel_launch(void* const* d_in, const int* in_sizes, int n_in,
                              void* d_out, int out_size, void* d_ws, size_t ws_size,
                              hipStream_t stream) {
    const float* node_feat = (const float*)d_in[0];
    const int*   edge_index = (const int*)d_in[1];
    const float* edge_feat = (const float*)d_in[2];
    const float* eps = (const float*)d_in[3];
    float* out = (float*)d_out;

    int ND = in_sizes[0];
    int N_ = ND / D;
    int E_ = in_sizes[1] / 2;
    const int* src = edge_index;
    const int* dst = edge_index + E_;

    size_t need = ((size_t)2 * N_ + 2) * sizeof(int) + (size_t)E_ * sizeof(v2i);
    if (ws_size < need) {
        // fallback: R0 atomic path
        int n4 = ND / 4;
        init_out_kernel<<<(n4 + 255) / 256, 256, 0, stream>>>(
            (const float4*)node_feat, eps, (float4*)out, n4);
        long long total = (long long)E_ * 32;
        int g2 = (int)((total + 255) / 256);
        edge_scatter_kernel<<<g2, 256, 0, stream>>>(
            (const float4*)node_feat, (const float4*)edge_feat, src, dst, out, E_);
        return;
    }

    int* cursor = (int*)d_ws;            // N ints (also deg histogram)
    int* offs   = cursor + N_;           // N+1 ints (+1 pad for v2i alignment)
    v2i* perm   = (v2i*)(offs + (N_ + 2)); // E int2, 8B-aligned

    // 1. zero the histogram
    hipMemsetAsync(cursor, 0, (size_t)N_ * sizeof(int), stream);
    // 2. histogram of dst
    histogram_kernel<<<(E_ + 255) / 256, 256, 0, stream>>>(dst, cursor, E_);
    // 3. exclusive scan -> offs, cursor
    scan_kernel<<<1, 1024, 0, stream>>>(cursor, offs, cursor, N_);
    // 4. scatter packed (src, eid) into CSR order
    scatter_perm_kernel<<<(E_ + 255) / 256, 256, 0, stream>>>(
        src, dst, cursor, perm, E_);
    // 5. aggregate: one wave per node, batched loads, single coalesced write
    int waves_per_block = 4;             // 256 threads
    int g = (N_ + waves_per_block - 1) / waves_per_block;
    aggregate_kernel<<<g, 256, 0, stream>>>(
        (const v2f*)node_feat, (const v2f*)edge_feat,
        offs, perm, eps, (v2f*)out, N_);
}